// Round 16
// baseline (118.173 us; speedup 1.0000x reference)
//
#include <hip/hip_runtime.h>

typedef unsigned short u16;
typedef __attribute__((ext_vector_type(8))) short short8;
typedef __attribute__((ext_vector_type(4))) float f32x4;

// ---------------- helpers ----------------

__device__ __forceinline__ u16 f2bf(float f) {
    unsigned u = __float_as_uint(f);
    u += 0x7fffu + ((u >> 16) & 1u);   // round-to-nearest-even
    return (u16)(u >> 16);
}

// async global->LDS 16B copy; per-lane dst == wave-uniform base + lane*16.
__device__ __forceinline__ void lds_cp16(const u16* g, u16* l) {
#if defined(__has_builtin) && __has_builtin(__builtin_amdgcn_global_load_lds)
    __builtin_amdgcn_global_load_lds(
        (const __attribute__((address_space(1))) void*)g,
        (__attribute__((address_space(3))) void*)l, 16, 0, 0);
#else
    *(uint4*)l = *(const uint4*)g;
#endif
}

// raw workgroup barrier with compiler memory fences (no vmcnt drain!)
__device__ __forceinline__ void bar() {
    asm volatile("" ::: "memory");
    __builtin_amdgcn_s_barrier();
    asm volatile("" ::: "memory");
}

// ---------------- champion core (kept for k_gemm_m) ----------------
template <int MI, bool ROWSUM>
__device__ __forceinline__ void gemm64(const u16* __restrict__ Ag, int lda,
                                       const u16* __restrict__ Bg, int ldb,
                                       int ksteps, u16* Alds, u16* Blds,
                                       f32x4 (&acc)[MI][4], f32x4* accL) {
    const int t = threadIdx.x;
    const int lane = t & 63, w = t >> 6;
    const int l15 = lane & 15, g4 = lane >> 4;
    const int wr = (w >> 1) * (MI * 16);
    const int wc = (w & 1) * 64;
    const int swz = l15 & 7;
    const short ob = (short)0x3f80;
    const short8 ones = {ob, ob, ob, ob, ob, ob, ob, ob};

    for (int kt = 0; kt < ksteps; ++kt) {
        __syncthreads();
#pragma unroll
        for (int p = 0; p < MI; ++p) {
            const int gi = t + p * 256;
            const int row = gi >> 3;
            const int gl = (gi & 7) ^ (row & 7);
            lds_cp16(Ag + (size_t)row * lda + kt * 64 + gl * 8, Alds + gi * 8);
        }
#pragma unroll
        for (int p = 0; p < 4; ++p) {
            const int gi = t + p * 256;
            const int row = gi >> 3;
            const int gl = (gi & 7) ^ (row & 7);
            lds_cp16(Bg + (size_t)row * ldb + kt * 64 + gl * 8, Blds + gi * 8);
        }
        __syncthreads();
#pragma unroll
        for (int ks = 0; ks < 2; ++ks) {
            short8 a[MI], b[4];
#pragma unroll
            for (int i = 0; i < MI; ++i) {
                const int r = wr + i * 16 + l15;
                a[i] = *(const short8*)(Alds + r * 64 + (((ks * 4 + g4) ^ swz) * 8));
            }
#pragma unroll
            for (int j = 0; j < 4; ++j) {
                const int r = wc + j * 16 + l15;
                b[j] = *(const short8*)(Blds + r * 64 + (((ks * 4 + g4) ^ swz) * 8));
            }
#pragma unroll
            for (int i = 0; i < MI; ++i)
#pragma unroll
                for (int j = 0; j < 4; ++j)
                    acc[i][j] = __builtin_amdgcn_mfma_f32_16x16x32_bf16(a[i], b[j], acc[i][j], 0, 0, 0);
            if constexpr (ROWSUM) {
#pragma unroll
                for (int i = 0; i < MI; ++i)
                    accL[i] = __builtin_amdgcn_mfma_f32_16x16x32_bf16(a[i], ones, accL[i], 0, 0, 0);
            }
        }
    }
}

// ---------------- NEW: counted-vmcnt 2-deep pipelined core, BK=32 ----------------
// Same LDS footprint, tiles, grids, and residency as the champion core — the ONLY
// change is the schedule: stage(s+1) stays IN FLIGHT across barriers (counted
// vmcnt, never 0 mid-loop), and stage(s+2) is issued before the MFMA cluster so
// its L2 latency is covered by ~2 iterations of compute. The champion core issues
// its stage and immediately drains it at the barrier (0 compute cover) — the
// hypothesized cause of the invariant ~20% MfmaUtil.
// Swizzle: granule pos = logical ^ ((row>>1)&3) (involution, identical on A and B
// -> cancels in MFMA; 2-way bank aliasing max). glds dst linear (rule 21), source
// granule inverse-permuted. GLD = glds per thread per stage = MI/2 + 2.
template <int MI, bool ROWSUM>
__device__ __forceinline__ void gemm32p(const u16* __restrict__ Ag, int lda,
                                        const u16* __restrict__ Bg, int ldb,
                                        int S /*BK32 steps, >=2*/, u16* Alds, u16* Blds,
                                        f32x4 (&acc)[MI][4], f32x4* accL) {
    const int t = threadIdx.x;
    const int lane = t & 63, w = t >> 6;
    const int l15 = lane & 15, g4 = lane >> 4;
    const int wr = (w >> 1) * (MI * 16);
    const int wc = (w & 1) * 64;
    const short ob = (short)0x3f80;
    const short8 ones = {ob, ob, ob, ob, ob, ob, ob, ob};

    auto stage = [&](int s, int buf) {
#pragma unroll
        for (int p = 0; p < MI / 2; ++p) {   // A: MI*32 rows x 4 granules
            const int gi = t + p * 256;
            const int row = gi >> 2, pos = gi & 3;
            const int gl = pos ^ ((row >> 1) & 3);
            lds_cp16(Ag + (size_t)row * lda + s * 32 + gl * 8, Alds + buf * (MI * 1024) + gi * 8);
        }
#pragma unroll
        for (int p = 0; p < 2; ++p) {        // B: 128 rows x 4 granules
            const int gi = t + p * 256;
            const int row = gi >> 2, pos = gi & 3;
            const int gl = pos ^ ((row >> 1) & 3);
            lds_cp16(Bg + (size_t)row * ldb + s * 32 + gl * 8, Blds + buf * 4096 + gi * 8);
        }
    };

    stage(0, 0);
    if (S > 1) stage(1, 1);
    for (int s = 0; s < S; ++s) {
        const int cur = s & 1;
        if (s + 1 < S) {   // counted: stage(s+1) (GLD ops) may stay in flight
            if constexpr (MI == 4) asm volatile("s_waitcnt vmcnt(4)" ::: "memory");
            else                   asm volatile("s_waitcnt vmcnt(3)" ::: "memory");
        } else {
            asm volatile("s_waitcnt vmcnt(0)" ::: "memory");
        }
        bar();   // every wave's stage(s) portion retired -> buf[cur] complete

        short8 a[MI], b[4];
#pragma unroll
        for (int i = 0; i < MI; ++i) {
            const int r = wr + i * 16 + l15;
            a[i] = *(const short8*)(Alds + cur * (MI * 1024) + r * 32 + ((g4 ^ ((r >> 1) & 3)) << 3));
        }
#pragma unroll
        for (int j = 0; j < 4; ++j) {
            const int r = wc + j * 16 + l15;
            b[j] = *(const short8*)(Blds + cur * 4096 + r * 32 + ((g4 ^ ((r >> 1) & 3)) << 3));
        }
        asm volatile("s_waitcnt lgkmcnt(0)" ::: "memory");  // reads retired (data in regs)
        __builtin_amdgcn_sched_barrier(0);                   // rule 18: pin order
        bar();   // all waves' reads of buf[cur] done -> safe to overwrite

        if (s + 2 < S) stage(s + 2, cur);  // glds latency covered by MFMA below

#pragma unroll
        for (int i = 0; i < MI; ++i)
#pragma unroll
            for (int j = 0; j < 4; ++j)
                acc[i][j] = __builtin_amdgcn_mfma_f32_16x16x32_bf16(a[i], b[j], acc[i][j], 0, 0, 0);
        if constexpr (ROWSUM) {
#pragma unroll
            for (int i = 0; i < MI; ++i)
                accL[i] = __builtin_amdgcn_mfma_f32_16x16x32_bf16(a[i], ones, accL[i], 0, 0, 0);
        }
    }
}

// ---------------- kernels ----------------

// fused input conversion: blocks [0,2048) -> data fp32->bf16; [2048,2816) -> weights
// (Wq,Wk native cast [k][n]; Wv transposed [n][k]).
__global__ void k_cvt(const float4* __restrict__ X4, ushort4* __restrict__ Xb4,
                      const float* __restrict__ Wq, const float* __restrict__ Wk,
                      const float* __restrict__ Wv, u16* __restrict__ Wt) {
    const int bid = blockIdx.x, t = threadIdx.x;
    if (bid < 2048) {
        const int n4 = (8 * 2048 * 512) / 4;
        for (int i = bid * 256 + t; i < n4; i += 2048 * 256) {
            float4 v = X4[i];
            ushort4 o;
            o.x = f2bf(v.x); o.y = f2bf(v.y); o.z = f2bf(v.z); o.w = f2bf(v.w);
            Xb4[i] = o;
        }
    } else {
        const int e0 = ((bid - 2048) * 256 + t) * 4;
#pragma unroll
        for (int p = 0; p < 4; ++p) {
            const int idx = e0 + p;
            const int z = idx >> 18;
            const int rem = idx & 262143;
            float v;
            if (z == 0) v = Wq[rem];
            else if (z == 1) v = Wk[rem];
            else { int n = rem >> 9, k = rem & 511; v = Wv[k * 512 + n]; }
            Wt[idx] = f2bf(v);
        }
    }
}

// M[e][f] = sum_n Wq[e,n]*Wk[f,n]; store Mt[f*512+e] = M[e][f]/sqrt(2048).
__global__ __launch_bounds__(256, 4) void k_gemm_m(const u16* __restrict__ Wt, u16* __restrict__ Mt) {
    __shared__ alignas(16) u16 Alds[8192];
    __shared__ alignas(16) u16 Blds[8192];
    const int mt = blockIdx.x & 3, nt = blockIdx.x >> 2;
    const u16* Ag = Wt + 0 * 512 * 512 + (size_t)mt * 128 * 512;
    const u16* Bg = Wt + 1 * 512 * 512 + (size_t)nt * 128 * 512;
    f32x4 acc[4][4] = {};
    gemm64<4, false>(Ag, 512, Bg, 512, 8, Alds, Blds, acc, (f32x4*)nullptr);

    const int t = threadIdx.x, lane = t & 63, w = t >> 6;
    const int wr = (w >> 1) * 64, wc = (w & 1) * 64;
    const float sc = 0.022097086912079608f;
#pragma unroll
    for (int i = 0; i < 4; ++i)
#pragma unroll
        for (int j = 0; j < 4; ++j)
#pragma unroll
            for (int r = 0; r < 4; ++r) {
                int e = mt * 128 + wr + i * 16 + 4 * (lane >> 4) + r;
                int f = nt * 128 + wc + j * 16 + (lane & 15);
                Mt[(size_t)f * 512 + e] = f2bf(acc[i][j][r] * sc);
            }
}

// projections: z=0 -> G = Xb*Mt^T (replaces Q; K projection deleted),
//              z=1 -> V stored transposed [b][d][s]. 128^2 tiles, XCD-chunked mt.
__global__ __launch_bounds__(256, 4) void k_proj(const u16* __restrict__ Xb, const u16* __restrict__ Wt,
                                                 const u16* __restrict__ Mt,
                                                 u16* __restrict__ Gb, u16* __restrict__ Vt) {
    __shared__ alignas(16) u16 Alds[8192];   // [2][128x32]
    __shared__ alignas(16) u16 Blds[8192];   // [2][128x32]
    const int bid = blockIdx.x;            // 1024 blocks
    const int u = bid >> 3;                // 0..127
    const int z = u >> 6;                  // 0..1
    const int nt = (u >> 4) & 3;           // 0..3
    const int mt = (bid & 7) * 16 + (u & 15);  // 0..127, XCD-chunked
    const u16* Ag = Xb + (size_t)mt * 128 * 512;
    const u16* Bg = (z == 0) ? (Mt + (size_t)nt * 128 * 512)
                             : (Wt + 2 * 512 * 512 + (size_t)nt * 128 * 512);
    f32x4 acc[4][4] = {};
    gemm32p<4, false>(Ag, 512, Bg, 512, 16, Alds, Blds, acc, (f32x4*)nullptr);

    const int t = threadIdx.x, lane = t & 63, w = t >> 6;
    const int wr = (w >> 1) * 64, wc = (w & 1) * 64;
    if (z == 0) {
#pragma unroll
        for (int i = 0; i < 4; ++i)
#pragma unroll
            for (int j = 0; j < 4; ++j)
#pragma unroll
                for (int r = 0; r < 4; ++r) {
                    int m = mt * 128 + wr + i * 16 + 4 * (lane >> 4) + r;
                    int n = nt * 128 + wc + j * 16 + (lane & 15);
                    Gb[(size_t)m * 512 + n] = f2bf(acc[i][j][r]);
                }
    } else {
        int b = mt >> 4;  // 16 m-tiles per batch
#pragma unroll
        for (int i = 0; i < 4; ++i)
#pragma unroll
            for (int j = 0; j < 4; ++j) {
                int s0 = (mt * 128 + wr + i * 16 + 4 * (lane >> 4)) & 2047;
                int d = nt * 128 + wc + j * 16 + (lane & 15);
                ushort4 pk;
                pk.x = f2bf(acc[i][j][0]); pk.y = f2bf(acc[i][j][1]);
                pk.z = f2bf(acc[i][j][2]); pk.w = f2bf(acc[i][j][3]);
                *(ushort4*)(Vt + (size_t)b * 512 * 2048 + (size_t)d * 2048 + s0) = pk;
            }
    }
}

// scores: P[b][q][kv] = exp(G . X) causal-masked, unnormalized, bf16.
// Compact triangular grid: 1088 = 8 bz x 136 tiles; bz = bid&7 (XCD/L2 affinity).
__global__ __launch_bounds__(256, 4) void k_scores(const u16* __restrict__ Gb, const u16* __restrict__ Xb,
                                                   u16* __restrict__ P) {
    const int bid = blockIdx.x;
    const int bz = bid & 7;
    const int tt = bid >> 3;  // 0..135
    int qi = (int)((sqrtf(8.0f * tt + 1.0f) - 1.0f) * 0.5f);
    while ((qi + 1) * (qi + 2) / 2 <= tt) ++qi;
    while (qi * (qi + 1) / 2 > tt) --qi;
    const int kvj = tt - qi * (qi + 1) / 2;  // 0..qi

    __shared__ alignas(16) u16 Alds[8192];
    __shared__ alignas(16) u16 Blds[8192];
    const u16* Ag = Gb + (size_t)bz * 2048 * 512 + (size_t)qi * 128 * 512;
    const u16* Bg = Xb + (size_t)bz * 2048 * 512 + (size_t)kvj * 128 * 512;
    f32x4 acc[4][4] = {};
    gemm32p<4, false>(Ag, 512, Bg, 512, 16, Alds, Blds, acc, (f32x4*)nullptr);

    const int t = threadIdx.x, lane = t & 63, w = t >> 6;
    const int wr = (w >> 1) * 64, wc = (w & 1) * 64;
    u16* Pb = P + (size_t)bz * 2048 * 2048;
#pragma unroll
    for (int i = 0; i < 4; ++i)
#pragma unroll
        for (int j = 0; j < 4; ++j)
#pragma unroll
            for (int r = 0; r < 4; ++r) {
                int q = qi * 128 + wr + i * 16 + 4 * (lane >> 4) + r;
                int kv = kvj * 128 + wc + j * 16 + (lane & 15);
                float pv = (kv <= q) ? __expf(acc[i][j][r]) : 0.0f;
                Pb[(size_t)q * 2048 + kv] = f2bf(pv);
            }
}

// PV: out = (P @ Vt) / rowsum(P); rowsum via ones-MFMA. 24KB LDS, 1024 blocks;
// bz = bid&7 (XCD/batch affinity); quarter mapping keeps per-CU work constant.
__global__ __launch_bounds__(256, 4) void k_pv(const u16* __restrict__ P, const u16* __restrict__ Vt,
                                               float* __restrict__ Out) {
    __shared__ alignas(16) u16 Alds[4096];   // [2][64x32]
    __shared__ alignas(16) u16 Blds[8192];   // [2][128x32]
    const int bid = blockIdx.x;
    const int bz = bid & 7;
    const int u = bid >> 3;        // 0..127
    const int g = u >> 5;          // quarter = nt
    const int s = u & 31;
    const int nt = g;
    const int qi2 = (g & 1) ? (31 - s) : s;   // 64-row q tile
    const int S = (qi2 + 1) * 2;              // BK32 steps (2..64)

    const u16* Ag = P + (size_t)bz * 2048 * 2048 + (size_t)qi2 * 64 * 2048;
    const u16* Bg = Vt + (size_t)bz * 512 * 2048 + (size_t)nt * 128 * 2048;
    f32x4 acc[2][4] = {};
    f32x4 accL[2] = {};
    gemm32p<2, true>(Ag, 2048, Bg, 2048, S, Alds, Blds, acc, accL);

    const int t = threadIdx.x, lane = t & 63, w = t >> 6;
    const int l = lane & 15, g4 = lane >> 4;
    const int wr = (w >> 1) * 32, wc = (w & 1) * 64;
#pragma unroll
    for (int i = 0; i < 2; ++i) {
        float inv[4];
#pragma unroll
        for (int r = 0; r < 4; ++r) inv[r] = 1.0f / accL[i][r];
#pragma unroll
        for (int j = 0; j < 4; ++j) {
            const int d = nt * 128 + wc + j * 16 + l;
#pragma unroll
            for (int r = 0; r < 4; ++r) {
                const int q = qi2 * 64 + wr + i * 16 + 4 * g4 + r;
                Out[(size_t)bz * 2048 * 512 + (size_t)q * 512 + d] = acc[i][j][r] * inv[r];
            }
        }
    }
}

// ---------------- launch ----------------

extern "C" void kernel_launch(void* const* d_in, const int* in_sizes, int n_in,
                              void* d_out, int out_size, void* d_ws, size_t ws_size,
                              hipStream_t stream) {
    const float* data = (const float*)d_in[0];
    const float* Wq = (const float*)d_in[1];
    const float* Wk = (const float*)d_in[2];
    const float* Wv = (const float*)d_in[3];
    float* out = (float*)d_out;
    char* ws = (char*)d_ws;

    // workspace layout (bytes)
    u16* Xb = (u16*)(ws);                 // 16 MB  [16384][512] bf16 data
    u16* Gb = (u16*)(ws + 16777216);      // 16 MB  G = X*M (replaces Q)
    u16* Mt = (u16*)(ws + 33554432);      // 512 KB [n'][k'] bf16 = M^T, scaled
    u16* Vt = (u16*)(ws + 50331648);      // 16 MB  V^T [b][d][s]
    u16* Wt = (u16*)(ws + 67108864);      // 1.5 MB bf16 {Wq native, Wk native, Wv^T}
    u16* P  = (u16*)(ws + 68681728);      // 64 MB  [b][q][kv] bf16 exp(scores)

    k_cvt<<<2816, 256, 0, stream>>>((const float4*)data, (ushort4*)Xb, Wq, Wk, Wv, Wt);
    k_gemm_m<<<16, 256, 0, stream>>>(Wt, Mt);
    k_proj<<<1024, 256, 0, stream>>>(Xb, Wt, Mt, Gb, Vt);
    k_scores<<<1088, 256, 0, stream>>>(Gb, Xb, P);
    k_pv<<<1024, 256, 0, stream>>>(P, Vt, out);
}

// Round 17
// 110.898 us; speedup vs baseline: 1.0656x; 1.0656x over previous
//
#include <hip/hip_runtime.h>

typedef unsigned short u16;
typedef __attribute__((ext_vector_type(8))) short short8;
typedef __attribute__((ext_vector_type(4))) float f32x4;

// ---------------- helpers ----------------

__device__ __forceinline__ u16 f2bf(float f) {
    unsigned u = __float_as_uint(f);
    u += 0x7fffu + ((u >> 16) & 1u);   // round-to-nearest-even
    return (u16)(u >> 16);
}

// async global->LDS 16B copy; per-lane dst == wave-uniform base + lane*16.
__device__ __forceinline__ void lds_cp16(const u16* g, u16* l) {
#if defined(__has_builtin) && __has_builtin(__builtin_amdgcn_global_load_lds)
    __builtin_amdgcn_global_load_lds(
        (const __attribute__((address_space(1))) void*)g,
        (__attribute__((address_space(3))) void*)l, 16, 0, 0);
#else
    *(uint4*)l = *(const uint4*)g;
#endif
}

// ---------------- shared GEMM core, BK=64, swizzled LDS (champion, 111us) ----------------
// C[(MI*32) x 128] += A * B^T; A row-major [row][k] (lda), Bt row-major [col][k] (ldb).
// 256 thr = 4 waves; wave w owns rows [(w>>1)*MI*16 ..) x cols [(w&1)*64 ..).
// LDS row stride 128B; granule g (16B) of row r stored at g^(r&7) (linear glds dst,
// SOURCE granule inverse-permuted). Reads XOR identically -> identity on data,
// 2-way bank aliasing max. K-granule permutation identical on A and B -> cancels in MFMA.
// Session ledger (final): refuted at this K=512 short-K regime — drain-dbuf (R5),
// 8-phase (R6), de-convoy skew (R9), 256-wide tiles (R11), forced occupancy via
// launch_bounds (R12, -34%: VGPR crush), equal-work pv split (R14), counted-vmcnt
// 2-deep pipeline (R16, -6%: 2x barriers + sched pin). Wins: XCD/L2 affinity,
// K-projection elimination, BK=64 swizzle, this 2-barrier core at 4 blocks/CU.
template <int MI, bool ROWSUM>
__device__ __forceinline__ void gemm64(const u16* __restrict__ Ag, int lda,
                                       const u16* __restrict__ Bg, int ldb,
                                       int ksteps, u16* Alds, u16* Blds,
                                       f32x4 (&acc)[MI][4], f32x4* accL) {
    const int t = threadIdx.x;
    const int lane = t & 63, w = t >> 6;
    const int l15 = lane & 15, g4 = lane >> 4;
    const int wr = (w >> 1) * (MI * 16);
    const int wc = (w & 1) * 64;
    const int swz = l15 & 7;
    const short ob = (short)0x3f80;  // bf16 1.0
    const short8 ones = {ob, ob, ob, ob, ob, ob, ob, ob};

    for (int kt = 0; kt < ksteps; ++kt) {
        __syncthreads();  // prior kstep's reads complete before overwrite
#pragma unroll
        for (int p = 0; p < MI; ++p) {  // A: MI*32 rows -> MI granules/thread
            const int gi = t + p * 256;
            const int row = gi >> 3;
            const int gl = (gi & 7) ^ (row & 7);
            lds_cp16(Ag + (size_t)row * lda + kt * 64 + gl * 8, Alds + gi * 8);
        }
#pragma unroll
        for (int p = 0; p < 4; ++p) {   // B: 128 rows -> 4 granules/thread
            const int gi = t + p * 256;
            const int row = gi >> 3;
            const int gl = (gi & 7) ^ (row & 7);
            lds_cp16(Bg + (size_t)row * ldb + kt * 64 + gl * 8, Blds + gi * 8);
        }
        __syncthreads();  // barrier drains vmcnt -> tile visible
#pragma unroll
        for (int ks = 0; ks < 2; ++ks) {
            short8 a[MI], b[4];
#pragma unroll
            for (int i = 0; i < MI; ++i) {
                const int r = wr + i * 16 + l15;
                a[i] = *(const short8*)(Alds + r * 64 + (((ks * 4 + g4) ^ swz) * 8));
            }
#pragma unroll
            for (int j = 0; j < 4; ++j) {
                const int r = wc + j * 16 + l15;
                b[j] = *(const short8*)(Blds + r * 64 + (((ks * 4 + g4) ^ swz) * 8));
            }
#pragma unroll
            for (int i = 0; i < MI; ++i)
#pragma unroll
                for (int j = 0; j < 4; ++j)
                    acc[i][j] = __builtin_amdgcn_mfma_f32_16x16x32_bf16(a[i], b[j], acc[i][j], 0, 0, 0);
            if constexpr (ROWSUM) {
#pragma unroll
                for (int i = 0; i < MI; ++i)
                    accL[i] = __builtin_amdgcn_mfma_f32_16x16x32_bf16(a[i], ones, accL[i], 0, 0, 0);
            }
        }
    }
}

// ---------------- kernels ----------------

// fused input conversion: blocks [0,2048) -> data fp32->bf16; [2048,2816) -> weights
// (Wq,Wk native cast [k][n]; Wv transposed [n][k]).
__global__ void k_cvt(const float4* __restrict__ X4, ushort4* __restrict__ Xb4,
                      const float* __restrict__ Wq, const float* __restrict__ Wk,
                      const float* __restrict__ Wv, u16* __restrict__ Wt) {
    const int bid = blockIdx.x, t = threadIdx.x;
    if (bid < 2048) {
        const int n4 = (8 * 2048 * 512) / 4;
        for (int i = bid * 256 + t; i < n4; i += 2048 * 256) {
            float4 v = X4[i];
            ushort4 o;
            o.x = f2bf(v.x); o.y = f2bf(v.y); o.z = f2bf(v.z); o.w = f2bf(v.w);
            Xb4[i] = o;
        }
    } else {
        const int e0 = ((bid - 2048) * 256 + t) * 4;
#pragma unroll
        for (int p = 0; p < 4; ++p) {
            const int idx = e0 + p;
            const int z = idx >> 18;
            const int rem = idx & 262143;
            float v;
            if (z == 0) v = Wq[rem];
            else if (z == 1) v = Wk[rem];
            else { int n = rem >> 9, k = rem & 511; v = Wv[k * 512 + n]; }
            Wt[idx] = f2bf(v);
        }
    }
}

// M[e][f] = sum_n Wq[e,n]*Wk[f,n]; store Mt[f*512+e] = M[e][f]/sqrt(2048).
__global__ __launch_bounds__(256, 4) void k_gemm_m(const u16* __restrict__ Wt, u16* __restrict__ Mt) {
    __shared__ alignas(16) u16 Alds[8192];
    __shared__ alignas(16) u16 Blds[8192];
    const int mt = blockIdx.x & 3, nt = blockIdx.x >> 2;
    const u16* Ag = Wt + 0 * 512 * 512 + (size_t)mt * 128 * 512;
    const u16* Bg = Wt + 1 * 512 * 512 + (size_t)nt * 128 * 512;
    f32x4 acc[4][4] = {};
    gemm64<4, false>(Ag, 512, Bg, 512, 8, Alds, Blds, acc, (f32x4*)nullptr);

    const int t = threadIdx.x, lane = t & 63, w = t >> 6;
    const int wr = (w >> 1) * 64, wc = (w & 1) * 64;
    const float sc = 0.022097086912079608f;
#pragma unroll
    for (int i = 0; i < 4; ++i)
#pragma unroll
        for (int j = 0; j < 4; ++j)
#pragma unroll
            for (int r = 0; r < 4; ++r) {
                int e = mt * 128 + wr + i * 16 + 4 * (lane >> 4) + r;
                int f = nt * 128 + wc + j * 16 + (lane & 15);
                Mt[(size_t)f * 512 + e] = f2bf(acc[i][j][r] * sc);
            }
}

// projections: z=0 -> G = Xb*Mt^T (replaces Q; K projection deleted),
//              z=1 -> V stored transposed [b][d][s]. 128^2 tiles, XCD-chunked mt.
__global__ __launch_bounds__(256, 4) void k_proj(const u16* __restrict__ Xb, const u16* __restrict__ Wt,
                                                 const u16* __restrict__ Mt,
                                                 u16* __restrict__ Gb, u16* __restrict__ Vt) {
    __shared__ alignas(16) u16 Alds[8192];
    __shared__ alignas(16) u16 Blds[8192];
    const int bid = blockIdx.x;            // 1024 blocks
    const int u = bid >> 3;                // 0..127
    const int z = u >> 6;                  // 0..1
    const int nt = (u >> 4) & 3;           // 0..3
    const int mt = (bid & 7) * 16 + (u & 15);  // 0..127, XCD-chunked
    const u16* Ag = Xb + (size_t)mt * 128 * 512;
    const u16* Bg = (z == 0) ? (Mt + (size_t)nt * 128 * 512)
                             : (Wt + 2 * 512 * 512 + (size_t)nt * 128 * 512);
    f32x4 acc[4][4] = {};
    gemm64<4, false>(Ag, 512, Bg, 512, 8, Alds, Blds, acc, (f32x4*)nullptr);

    const int t = threadIdx.x, lane = t & 63, w = t >> 6;
    const int wr = (w >> 1) * 64, wc = (w & 1) * 64;
    if (z == 0) {
#pragma unroll
        for (int i = 0; i < 4; ++i)
#pragma unroll
            for (int j = 0; j < 4; ++j)
#pragma unroll
                for (int r = 0; r < 4; ++r) {
                    int m = mt * 128 + wr + i * 16 + 4 * (lane >> 4) + r;
                    int n = nt * 128 + wc + j * 16 + (lane & 15);
                    Gb[(size_t)m * 512 + n] = f2bf(acc[i][j][r]);
                }
    } else {
        int b = mt >> 4;  // 16 m-tiles per batch
#pragma unroll
        for (int i = 0; i < 4; ++i)
#pragma unroll
            for (int j = 0; j < 4; ++j) {
                int s0 = (mt * 128 + wr + i * 16 + 4 * (lane >> 4)) & 2047;
                int d = nt * 128 + wc + j * 16 + (lane & 15);
                ushort4 pk;
                pk.x = f2bf(acc[i][j][0]); pk.y = f2bf(acc[i][j][1]);
                pk.z = f2bf(acc[i][j][2]); pk.w = f2bf(acc[i][j][3]);
                *(ushort4*)(Vt + (size_t)b * 512 * 2048 + (size_t)d * 2048 + s0) = pk;
            }
    }
}

// scores: P[b][q][kv] = exp(G . X) causal-masked, unnormalized, bf16.
// Compact triangular grid: 1088 = 8 bz x 136 tiles; bz = bid&7 (XCD/L2 affinity).
__global__ __launch_bounds__(256, 4) void k_scores(const u16* __restrict__ Gb, const u16* __restrict__ Xb,
                                                   u16* __restrict__ P) {
    const int bid = blockIdx.x;
    const int bz = bid & 7;
    const int tt = bid >> 3;  // 0..135
    int qi = (int)((sqrtf(8.0f * tt + 1.0f) - 1.0f) * 0.5f);
    while ((qi + 1) * (qi + 2) / 2 <= tt) ++qi;
    while (qi * (qi + 1) / 2 > tt) --qi;
    const int kvj = tt - qi * (qi + 1) / 2;  // 0..qi

    __shared__ alignas(16) u16 Alds[8192];
    __shared__ alignas(16) u16 Blds[8192];
    const u16* Ag = Gb + (size_t)bz * 2048 * 512 + (size_t)qi * 128 * 512;
    const u16* Bg = Xb + (size_t)bz * 2048 * 512 + (size_t)kvj * 128 * 512;
    f32x4 acc[4][4] = {};
    gemm64<4, false>(Ag, 512, Bg, 512, 8, Alds, Blds, acc, (f32x4*)nullptr);

    const int t = threadIdx.x, lane = t & 63, w = t >> 6;
    const int wr = (w >> 1) * 64, wc = (w & 1) * 64;
    u16* Pb = P + (size_t)bz * 2048 * 2048;
#pragma unroll
    for (int i = 0; i < 4; ++i)
#pragma unroll
        for (int j = 0; j < 4; ++j)
#pragma unroll
            for (int r = 0; r < 4; ++r) {
                int q = qi * 128 + wr + i * 16 + 4 * (lane >> 4) + r;
                int kv = kvj * 128 + wc + j * 16 + (lane & 15);
                float pv = (kv <= q) ? __expf(acc[i][j][r]) : 0.0f;
                Pb[(size_t)q * 2048 + kv] = f2bf(pv);
            }
}

// PV: out = (P @ Vt) / rowsum(P); rowsum via ones-MFMA. BK=64, 24KB LDS.
// 1024 blocks; bz = bid&7 (XCD/batch affinity); quarter mapping keeps per-CU
// work constant (pairs qi2 and 31-qi2).
__global__ __launch_bounds__(256, 4) void k_pv(const u16* __restrict__ P, const u16* __restrict__ Vt,
                                               float* __restrict__ Out) {
    __shared__ alignas(16) u16 Alds[4096];   // 64q x 64kv
    __shared__ alignas(16) u16 Blds[8192];   // 128d x 64kv
    const int bid = blockIdx.x;
    const int bz = bid & 7;
    const int u = bid >> 3;        // 0..127
    const int g = u >> 5;          // quarter = nt
    const int s = u & 31;
    const int nt = g;
    const int qi2 = (g & 1) ? (31 - s) : s;   // 64-row q tile
    const int ksteps = qi2 + 1;               // causal extent in 64-wide kv tiles

    const u16* Ag = P + (size_t)bz * 2048 * 2048 + (size_t)qi2 * 64 * 2048;
    const u16* Bg = Vt + (size_t)bz * 512 * 2048 + (size_t)nt * 128 * 2048;
    f32x4 acc[2][4] = {};
    f32x4 accL[2] = {};
    gemm64<2, true>(Ag, 2048, Bg, 2048, ksteps, Alds, Blds, acc, accL);

    const int t = threadIdx.x, lane = t & 63, w = t >> 6;
    const int l = lane & 15, g4 = lane >> 4;
    const int wr = (w >> 1) * 32, wc = (w & 1) * 64;
#pragma unroll
    for (int i = 0; i < 2; ++i) {
        float inv[4];
#pragma unroll
        for (int r = 0; r < 4; ++r) inv[r] = 1.0f / accL[i][r];
#pragma unroll
        for (int j = 0; j < 4; ++j) {
            const int d = nt * 128 + wc + j * 16 + l;
#pragma unroll
            for (int r = 0; r < 4; ++r) {
                const int q = qi2 * 64 + wr + i * 16 + 4 * g4 + r;
                Out[(size_t)bz * 2048 * 512 + (size_t)q * 512 + d] = acc[i][j][r] * inv[r];
            }
        }
    }
}

// ---------------- launch ----------------

extern "C" void kernel_launch(void* const* d_in, const int* in_sizes, int n_in,
                              void* d_out, int out_size, void* d_ws, size_t ws_size,
                              hipStream_t stream) {
    const float* data = (const float*)d_in[0];
    const float* Wq = (const float*)d_in[1];
    const float* Wk = (const float*)d_in[2];
    const float* Wv = (const float*)d_in[3];
    float* out = (float*)d_out;
    char* ws = (char*)d_ws;

    // workspace layout (bytes)
    u16* Xb = (u16*)(ws);                 // 16 MB  [16384][512] bf16 data
    u16* Gb = (u16*)(ws + 16777216);      // 16 MB  G = X*M (replaces Q)
    u16* Mt = (u16*)(ws + 33554432);      // 512 KB [n'][k'] bf16 = M^T, scaled
    u16* Vt = (u16*)(ws + 50331648);      // 16 MB  V^T [b][d][s]
    u16* Wt = (u16*)(ws + 67108864);      // 1.5 MB bf16 {Wq native, Wk native, Wv^T}
    u16* P  = (u16*)(ws + 68681728);      // 64 MB  [b][q][kv] bf16 exp(scores)

    k_cvt<<<2816, 256, 0, stream>>>((const float4*)data, (ushort4*)Xb, Wq, Wk, Wv, Wt);
    k_gemm_m<<<16, 256, 0, stream>>>(Wt, Mt);
    k_proj<<<1024, 256, 0, stream>>>(Xb, Wt, Mt, Gb, Vt);
    k_scores<<<1088, 256, 0, stream>>>(Gb, Xb, P);
    k_pv<<<1024, 256, 0, stream>>>(P, Vt, out);
}